// Round 11
// baseline (1002.122 us; speedup 1.0000x reference)
//
#include <hip/hip_runtime.h>

#define FEAT 512
#define F4   128          // float4 per row
#define NSEG 1024
#define CHUNK 256         // rows per block

typedef float f4_t __attribute__((ext_vector_type(4)));

// ---------------- K1: segment boundaries + zero sums/cnt ----------------
__global__ void bounds_zero_kernel(const int* __restrict__ seg,
                                   int* __restrict__ starts,
                                   float* __restrict__ sums,
                                   int* __restrict__ cnt, int total) {
    int i = blockIdx.x * blockDim.x + threadIdx.x;
    if (sums != nullptr && i < NSEG * FEAT / 2) {
        ((float2*)sums)[i] = make_float2(0.f, 0.f);
    }
    if (cnt != nullptr && i < NSEG) cnt[i] = 0;
    if (i >= total) return;
    int cur = seg[i];
    int prev = (i == 0) ? -1 : seg[i - 1];
    for (int s = prev + 1; s <= cur; ++s) starts[s] = i;
    if (i == total - 1) {
        for (int s = cur + 1; s <= NSEG; ++s) starts[s] = total;
    }
}

__device__ __forceinline__ void bcast_rows(f4_t* __restrict__ o4, f4_t mean,
                                           int ra, int rb, int rg) {
    int r = ra + rg;
    for (; r + 28 < rb; r += 32) {
        f4_t* q = o4 + (size_t)r * F4;
        __builtin_nontemporal_store(mean, q + 0 * 4 * F4);
        __builtin_nontemporal_store(mean, q + 1 * 4 * F4);
        __builtin_nontemporal_store(mean, q + 2 * 4 * F4);
        __builtin_nontemporal_store(mean, q + 3 * 4 * F4);
        __builtin_nontemporal_store(mean, q + 4 * 4 * F4);
        __builtin_nontemporal_store(mean, q + 5 * 4 * F4);
        __builtin_nontemporal_store(mean, q + 6 * 4 * F4);
        __builtin_nontemporal_store(mean, q + 7 * 4 * F4);
    }
    for (; r < rb; r += 4) {
        __builtin_nontemporal_store(mean, o4 + (size_t)r * F4);
    }
}

// ---------------- K2: fused sum + completion-triggered broadcast ----------------
// Each block sums its CHUNK rows (R7's proven NT x8 loop). Boundary segments:
// atomic partial flush -> threadfence -> arrival-counter bump; the completing
// block reads the finished sum (agent-scope, L1-bypass) and broadcasts the
// WHOLE segment. Sole-contributor segments broadcast directly from registers.
// No grid barriers: reads and writes mix chip-wide for the kernel's duration.
__global__ __launch_bounds__(512) void fused_dataflow_kernel(
        const float* __restrict__ batch,
        const int* __restrict__ seg,
        const int* __restrict__ starts,
        float* __restrict__ sums,
        int* __restrict__ cnt,
        float* __restrict__ out, int total) {
    const int tid  = threadIdx.x;
    const int lane = tid & (F4 - 1);   // f4 column 0..127
    const int rg   = tid >> 7;         // row-group 0..3
    const int r0   = blockIdx.x * CHUNK;
    if (r0 >= total) return;
    const int r1   = min(r0 + CHUNK, total);

    const int s0 = seg[r0];
    const int s1 = seg[r1 - 1];

    const f4_t* b4 = (const f4_t*)batch;
    f4_t* o4 = (f4_t*)out;
    __shared__ f4_t red[4][F4];
    __shared__ int win;

    for (int s = s0; s <= s1; ++s) {
        const int sa = starts[s];
        const int sb = starts[s + 1];
        const int a = max(sa, r0);     // block-uniform
        const int b = min(sb, r1);     // block-uniform
        if (a >= b) continue;          // empty segment (uniform skip)

        // ---- sum rows [a,b) : R7's x8-unrolled NT read loop ----
        f4_t a0 = (f4_t)(0.f);
        f4_t a1 = (f4_t)(0.f);
        int r = a + rg;
        for (; r + 28 < b; r += 32) {
            const f4_t* p = b4 + (size_t)r * F4 + lane;
            f4_t v0 = __builtin_nontemporal_load(p + 0 * 4 * F4);
            f4_t v1 = __builtin_nontemporal_load(p + 1 * 4 * F4);
            f4_t v2 = __builtin_nontemporal_load(p + 2 * 4 * F4);
            f4_t v3 = __builtin_nontemporal_load(p + 3 * 4 * F4);
            f4_t v4 = __builtin_nontemporal_load(p + 4 * 4 * F4);
            f4_t v5 = __builtin_nontemporal_load(p + 5 * 4 * F4);
            f4_t v6 = __builtin_nontemporal_load(p + 6 * 4 * F4);
            f4_t v7 = __builtin_nontemporal_load(p + 7 * 4 * F4);
            a0 += v0; a1 += v1;
            a0 += v2; a1 += v3;
            a0 += v4; a1 += v5;
            a0 += v6; a1 += v7;
        }
        for (; r < b; r += 4) {
            a0 += __builtin_nontemporal_load(b4 + (size_t)r * F4 + lane);
        }
        a0 += a1;

        red[rg][lane] = a0;
        __syncthreads();

        const bool sole = (sa >= r0) && (sb <= r1);   // block-uniform
        if (sole) {
            // ---- fast path: this block owns the whole segment ----
            if (rg == 0) {
                f4_t t = red[0][lane] + red[1][lane] + red[2][lane] + red[3][lane];
                red[0][lane] = t * (1.0f / (float)(sb - sa));
            }
            __syncthreads();
            const f4_t mean = red[0][lane];
            __syncthreads();                 // red safe to reuse next iter
            bcast_rows(o4 + lane, mean, sa, sb, rg);
        } else {
            // ---- boundary path: atomic partial + completion counter ----
            if (rg == 0) {
                f4_t t = red[0][lane] + red[1][lane] + red[2][lane] + red[3][lane];
                float* dst = sums + (size_t)s * FEAT + lane * 4;
                atomicAdd(dst + 0, t.x);
                atomicAdd(dst + 1, t.y);
                atomicAdd(dst + 2, t.z);
                atomicAdd(dst + 3, t.w);
            }
            __threadfence();                 // partials visible device-wide
            __syncthreads();                 // all flushes in block complete
            if (tid == 0) {
                const int need = (sb - 1) / CHUNK - sa / CHUNK + 1;
                const int old  = atomicAdd(cnt + s, 1);
                win = (old == need - 1);
            }
            __syncthreads();
            if (win) {
                // last contributor: sum is complete at L2. Agent-scope loads
                // bypass L1 (other blocks' atomics never entered our L1).
                const float* src = sums + (size_t)s * FEAT + lane * 4;
                f4_t t;
                t.x = __hip_atomic_load(src + 0, __ATOMIC_RELAXED, __HIP_MEMORY_SCOPE_AGENT);
                t.y = __hip_atomic_load(src + 1, __ATOMIC_RELAXED, __HIP_MEMORY_SCOPE_AGENT);
                t.z = __hip_atomic_load(src + 2, __ATOMIC_RELAXED, __HIP_MEMORY_SCOPE_AGENT);
                t.w = __hip_atomic_load(src + 3, __ATOMIC_RELAXED, __HIP_MEMORY_SCOPE_AGENT);
                const f4_t mean = t * (1.0f / (float)(sb - sa));
                bcast_rows(o4 + lane, mean, sa, sb, rg);
            }
            __syncthreads();                 // red safe to reuse next iter
        }
    }
}

// ---------------- Fallback: R5 fused kernel (needs only ~4KB ws) --------------
__global__ __launch_bounds__(512) void seg_mean_fused_kernel(
        const float* __restrict__ batch,
        const int* __restrict__ starts,
        float* __restrict__ out) {
    const int s      = blockIdx.x;
    const int tid    = threadIdx.x;
    const int lane_f = tid & (F4 - 1);
    const int rgrp   = tid >> 7;

    const int start = starts[s];
    const int end   = starts[s + 1];
    const int count = end - start;

    const f4_t* b4 = (const f4_t*)batch;
    f4_t a0 = (f4_t)(0.f);
    f4_t a1 = (f4_t)(0.f);

    int r = start + rgrp;
    for (; r + 28 < end; r += 32) {
        const f4_t* p = b4 + (size_t)r * F4 + lane_f;
        f4_t v0 = __builtin_nontemporal_load(p + 0 * 4 * F4);
        f4_t v1 = __builtin_nontemporal_load(p + 1 * 4 * F4);
        f4_t v2 = __builtin_nontemporal_load(p + 2 * 4 * F4);
        f4_t v3 = __builtin_nontemporal_load(p + 3 * 4 * F4);
        f4_t v4 = __builtin_nontemporal_load(p + 4 * 4 * F4);
        f4_t v5 = __builtin_nontemporal_load(p + 5 * 4 * F4);
        f4_t v6 = __builtin_nontemporal_load(p + 6 * 4 * F4);
        f4_t v7 = __builtin_nontemporal_load(p + 7 * 4 * F4);
        a0 += v0; a1 += v1;
        a0 += v2; a1 += v3;
        a0 += v4; a1 += v5;
        a0 += v6; a1 += v7;
    }
    for (; r < end; r += 4) {
        a0 += __builtin_nontemporal_load(b4 + (size_t)r * F4 + lane_f);
    }
    a0 += a1;

    __shared__ f4_t red[4][F4];
    red[rgrp][lane_f] = a0;
    __syncthreads();

    if (rgrp == 0) {
        f4_t p0 = red[0][lane_f];
        f4_t p1 = red[1][lane_f];
        f4_t p2 = red[2][lane_f];
        f4_t p3 = red[3][lane_f];
        const float inv = 1.0f / (float)(count > 0 ? count : 1);
        red[0][lane_f] = (p0 + p1 + p2 + p3) * inv;
    }
    __syncthreads();

    const f4_t mean = red[0][lane_f];
    f4_t* o4 = (f4_t*)out;

    r = start + rgrp;
    for (; r + 28 < end; r += 32) {
        f4_t* q = o4 + (size_t)r * F4 + lane_f;
        __builtin_nontemporal_store(mean, q + 0 * 4 * F4);
        __builtin_nontemporal_store(mean, q + 1 * 4 * F4);
        __builtin_nontemporal_store(mean, q + 2 * 4 * F4);
        __builtin_nontemporal_store(mean, q + 3 * 4 * F4);
        __builtin_nontemporal_store(mean, q + 4 * 4 * F4);
        __builtin_nontemporal_store(mean, q + 5 * 4 * F4);
        __builtin_nontemporal_store(mean, q + 6 * 4 * F4);
        __builtin_nontemporal_store(mean, q + 7 * 4 * F4);
    }
    for (; r < end; r += 4) {
        __builtin_nontemporal_store(mean, o4 + (size_t)r * F4 + lane_f);
    }
}

extern "C" void kernel_launch(void* const* d_in, const int* in_sizes, int n_in,
                              void* d_out, int out_size, void* d_ws, size_t ws_size,
                              hipStream_t stream) {
    const float* batch = (const float*)d_in[0];
    const int*   seg   = (const int*)d_in[1];
    float*       out   = (float*)d_out;
    const int total    = in_sizes[1];

    // ws layout: [sums: 2MB][starts: (NSEG+1)*4 @2MB][cnt: NSEG*4 @2MB+8192]
    const size_t sums_bytes = (size_t)NSEG * FEAT * sizeof(float);
    const size_t starts_off = sums_bytes;
    const size_t cnt_off    = sums_bytes + 8192;
    const size_t need       = cnt_off + NSEG * sizeof(int);

    const int nblk256 = (total + 255) / 256;

    if (ws_size >= need) {
        float* sums   = (float*)d_ws;
        int*   starts = (int*)((char*)d_ws + starts_off);
        int*   cnt    = (int*)((char*)d_ws + cnt_off);

        bounds_zero_kernel<<<nblk256, 256, 0, stream>>>(seg, starts, sums, cnt, total);
        const int nchunks = (total + CHUNK - 1) / CHUNK;
        fused_dataflow_kernel<<<nchunks, 512, 0, stream>>>(batch, seg, starts, sums, cnt, out, total);
    } else {
        int* starts = (int*)d_ws;
        bounds_zero_kernel<<<nblk256, 256, 0, stream>>>(seg, starts, nullptr, nullptr, total);
        seg_mean_fused_kernel<<<NSEG, 512, 0, stream>>>(batch, starts, out);
    }
}

// Round 12
// 208.697 us; speedup vs baseline: 4.8018x; 4.8018x over previous
//
#include <hip/hip_runtime.h>

#define FEAT 512
#define F4   128          // float4 per row
#define NSEG 1024
#define CHUNK 256         // rows per block in sum/broadcast passes

typedef float f4_t __attribute__((ext_vector_type(4)));

// ---------------- K1: segment boundaries + zero sums ----------------
__global__ void bounds_zero_kernel(const int* __restrict__ seg,
                                   int* __restrict__ starts,
                                   float* __restrict__ sums, int total) {
    int i = blockIdx.x * blockDim.x + threadIdx.x;
    if (sums != nullptr && i < NSEG * FEAT / 2) {
        ((float2*)sums)[i] = make_float2(0.f, 0.f);
    }
    if (i >= total) return;
    int cur = seg[i];
    int prev = (i == 0) ? -1 : seg[i - 1];
    for (int s = prev + 1; s <= cur; ++s) starts[s] = i;
    if (i == total - 1) {
        for (int s = cur + 1; s <= NSEG; ++s) starts[s] = total;
    }
}

// ---------------- K2: chunk-balanced partial sums (read 512MB, CACHED loads) ----
// EXPERIMENT vs R7: loads are plain/cached (L2+L3 allocate), stores stay NT.
// Each block owns exactly CHUNK rows. 512 threads = 4 row-groups x 128
// f4-columns, x8-unrolled reads -> register acc -> LDS combine -> rg0
// flushes 4 scalar atomicAdds per segment.
__global__ __launch_bounds__(512) void chunk_sum_kernel(
        const float* __restrict__ batch,
        const int* __restrict__ seg,
        const int* __restrict__ starts,
        float* __restrict__ sums, int total) {
    const int tid  = threadIdx.x;
    const int lane = tid & (F4 - 1);   // f4 column 0..127
    const int rg   = tid >> 7;         // row-group 0..3
    const int r0   = blockIdx.x * CHUNK;
    if (r0 >= total) return;
    const int r1   = min(r0 + CHUNK, total);

    const int s0 = seg[r0];
    const int s1 = seg[r1 - 1];

    const f4_t* b4 = (const f4_t*)batch;
    __shared__ f4_t red[4][F4];

    for (int s = s0; s <= s1; ++s) {
        const int a = max(starts[s], r0);      // block-uniform
        const int b = min(starts[s + 1], r1);  // block-uniform
        if (a >= b) continue;                  // uniform skip (empty segment)

        f4_t a0 = (f4_t)(0.f);
        f4_t a1 = (f4_t)(0.f);
        int r = a + rg;
        for (; r + 28 < b; r += 32) {
            const f4_t* p = b4 + (size_t)r * F4 + lane;
            f4_t v0 = p[0 * 4 * F4];
            f4_t v1 = p[1 * 4 * F4];
            f4_t v2 = p[2 * 4 * F4];
            f4_t v3 = p[3 * 4 * F4];
            f4_t v4 = p[4 * 4 * F4];
            f4_t v5 = p[5 * 4 * F4];
            f4_t v6 = p[6 * 4 * F4];
            f4_t v7 = p[7 * 4 * F4];
            a0 += v0; a1 += v1;
            a0 += v2; a1 += v3;
            a0 += v4; a1 += v5;
            a0 += v6; a1 += v7;
        }
        for (; r < b; r += 4) {
            a0 += b4[(size_t)r * F4 + lane];
        }
        a0 += a1;

        red[rg][lane] = a0;
        __syncthreads();
        if (rg == 0) {
            f4_t t = red[0][lane] + red[1][lane] + red[2][lane] + red[3][lane];
            float* dst = sums + (size_t)s * FEAT + lane * 4;
            atomicAdd(dst + 0, t.x);
            atomicAdd(dst + 1, t.y);
            atomicAdd(dst + 2, t.z);
            atomicAdd(dst + 3, t.w);
        }
        __syncthreads();
    }
}

// ---------------- K3: chunk-balanced broadcast (write 512MB, NT stores) --------
__global__ __launch_bounds__(256) void broadcast_chunk_kernel(
        const int* __restrict__ seg,
        const int* __restrict__ starts,
        const float* __restrict__ sums,
        float* __restrict__ out, int total) {
    const int tid  = threadIdx.x;
    const int lane = tid & (F4 - 1);   // f4 column 0..127
    const int rg   = tid >> 7;         // row-group 0..1
    const int r0   = blockIdx.x * CHUNK;
    if (r0 >= total) return;
    const int r1   = min(r0 + CHUNK, total);

    const int s0 = seg[r0];
    const int s1 = seg[r1 - 1];

    const f4_t* m4 = (const f4_t*)sums;
    f4_t* o4 = (f4_t*)out;

    for (int s = s0; s <= s1; ++s) {
        const int sa = starts[s];
        const int sb = starts[s + 1];
        const int a = max(sa, r0);
        const int b = min(sb, r1);
        if (a >= b) continue;
        const int count = sb - sa;
        const float inv = 1.0f / (float)(count > 0 ? count : 1);
        const f4_t mean = m4[(size_t)s * F4 + lane] * inv;
        int r = a + rg;
        for (; r + 14 < b; r += 16) {
            f4_t* q = o4 + (size_t)r * F4 + lane;
            __builtin_nontemporal_store(mean, q + 0 * 2 * F4);
            __builtin_nontemporal_store(mean, q + 1 * 2 * F4);
            __builtin_nontemporal_store(mean, q + 2 * 2 * F4);
            __builtin_nontemporal_store(mean, q + 3 * 2 * F4);
            __builtin_nontemporal_store(mean, q + 4 * 2 * F4);
            __builtin_nontemporal_store(mean, q + 5 * 2 * F4);
            __builtin_nontemporal_store(mean, q + 6 * 2 * F4);
            __builtin_nontemporal_store(mean, q + 7 * 2 * F4);
        }
        for (; r < b; r += 2) {
            __builtin_nontemporal_store(mean, o4 + (size_t)r * F4 + lane);
        }
    }
}

// ---------------- Fallback: R5 fused kernel (needs only ~4KB ws) --------------
__global__ __launch_bounds__(512) void seg_mean_fused_kernel(
        const float* __restrict__ batch,
        const int* __restrict__ starts,
        float* __restrict__ out) {
    const int s      = blockIdx.x;
    const int tid    = threadIdx.x;
    const int lane_f = tid & (F4 - 1);
    const int rgrp   = tid >> 7;

    const int start = starts[s];
    const int end   = starts[s + 1];
    const int count = end - start;

    const f4_t* b4 = (const f4_t*)batch;
    f4_t a0 = (f4_t)(0.f);
    f4_t a1 = (f4_t)(0.f);

    int r = start + rgrp;
    for (; r + 28 < end; r += 32) {
        const f4_t* p = b4 + (size_t)r * F4 + lane_f;
        f4_t v0 = __builtin_nontemporal_load(p + 0 * 4 * F4);
        f4_t v1 = __builtin_nontemporal_load(p + 1 * 4 * F4);
        f4_t v2 = __builtin_nontemporal_load(p + 2 * 4 * F4);
        f4_t v3 = __builtin_nontemporal_load(p + 3 * 4 * F4);
        f4_t v4 = __builtin_nontemporal_load(p + 4 * 4 * F4);
        f4_t v5 = __builtin_nontemporal_load(p + 5 * 4 * F4);
        f4_t v6 = __builtin_nontemporal_load(p + 6 * 4 * F4);
        f4_t v7 = __builtin_nontemporal_load(p + 7 * 4 * F4);
        a0 += v0; a1 += v1;
        a0 += v2; a1 += v3;
        a0 += v4; a1 += v5;
        a0 += v6; a1 += v7;
    }
    for (; r < end; r += 4) {
        a0 += __builtin_nontemporal_load(b4 + (size_t)r * F4 + lane_f);
    }
    a0 += a1;

    __shared__ f4_t red[4][F4];
    red[rgrp][lane_f] = a0;
    __syncthreads();

    if (rgrp == 0) {
        f4_t p0 = red[0][lane_f];
        f4_t p1 = red[1][lane_f];
        f4_t p2 = red[2][lane_f];
        f4_t p3 = red[3][lane_f];
        const float inv = 1.0f / (float)(count > 0 ? count : 1);
        red[0][lane_f] = (p0 + p1 + p2 + p3) * inv;
    }
    __syncthreads();

    const f4_t mean = red[0][lane_f];
    f4_t* o4 = (f4_t*)out;

    r = start + rgrp;
    for (; r + 28 < end; r += 32) {
        f4_t* q = o4 + (size_t)r * F4 + lane_f;
        __builtin_nontemporal_store(mean, q + 0 * 4 * F4);
        __builtin_nontemporal_store(mean, q + 1 * 4 * F4);
        __builtin_nontemporal_store(mean, q + 2 * 4 * F4);
        __builtin_nontemporal_store(mean, q + 3 * 4 * F4);
        __builtin_nontemporal_store(mean, q + 4 * 4 * F4);
        __builtin_nontemporal_store(mean, q + 5 * 4 * F4);
        __builtin_nontemporal_store(mean, q + 6 * 4 * F4);
        __builtin_nontemporal_store(mean, q + 7 * 4 * F4);
    }
    for (; r < end; r += 4) {
        __builtin_nontemporal_store(mean, o4 + (size_t)r * F4 + lane_f);
    }
}

extern "C" void kernel_launch(void* const* d_in, const int* in_sizes, int n_in,
                              void* d_out, int out_size, void* d_ws, size_t ws_size,
                              hipStream_t stream) {
    const float* batch = (const float*)d_in[0];
    const int*   seg   = (const int*)d_in[1];
    float*       out   = (float*)d_out;
    const int total    = in_sizes[1];

    // ws layout: [sums: 2MB][starts: (NSEG+1)*4]
    const size_t sums_bytes = (size_t)NSEG * FEAT * sizeof(float);
    const size_t need       = sums_bytes + (NSEG + 1) * sizeof(int);

    const int nblk256 = (total + 255) / 256;

    if (ws_size >= need) {
        float* sums   = (float*)d_ws;
        int*   starts = (int*)((char*)d_ws + sums_bytes);

        bounds_zero_kernel<<<nblk256, 256, 0, stream>>>(seg, starts, sums, total);
        const int nchunks = (total + CHUNK - 1) / CHUNK;
        chunk_sum_kernel<<<nchunks, 512, 0, stream>>>(batch, seg, starts, sums, total);
        broadcast_chunk_kernel<<<nchunks, 256, 0, stream>>>(seg, starts, sums, out, total);
    } else {
        int* starts = (int*)d_ws;
        bounds_zero_kernel<<<nblk256, 256, 0, stream>>>(seg, starts, nullptr, total);
        seg_mean_fused_kernel<<<NSEG, 512, 0, stream>>>(batch, starts, out);
    }
}

// Round 13
// 203.269 us; speedup vs baseline: 4.9300x; 1.0267x over previous
//
#include <hip/hip_runtime.h>

#define FEAT 512
#define F4   128          // float4 per row
#define NSEG 1024
#define CHUNK 256         // rows per block

typedef float f4_t __attribute__((ext_vector_type(4)));

// ---------------- K1: segment boundaries + zero sums ----------------
__global__ void bounds_zero_kernel(const int* __restrict__ seg,
                                   int* __restrict__ starts,
                                   float* __restrict__ sums, int total) {
    int i = blockIdx.x * blockDim.x + threadIdx.x;
    if (sums != nullptr && i < NSEG * FEAT / 2) {
        ((float2*)sums)[i] = make_float2(0.f, 0.f);
    }
    if (i >= total) return;
    int cur = seg[i];
    int prev = (i == 0) ? -1 : seg[i - 1];
    for (int s = prev + 1; s <= cur; ++s) starts[s] = i;
    if (i == total - 1) {
        for (int s = cur + 1; s <= NSEG; ++s) starts[s] = total;
    }
}

// ---- device helpers: R7's proven NT x8 loop bodies ----
__device__ __forceinline__ void sum_chunk_body(
        const f4_t* __restrict__ b4, const int* __restrict__ seg,
        const int* __restrict__ starts, float* __restrict__ sums,
        f4_t (*red)[F4], int r0, int r1, int lane, int rg) {
    const int s0 = seg[r0];
    const int s1 = seg[r1 - 1];
    for (int s = s0; s <= s1; ++s) {
        const int a = max(starts[s], r0);
        const int b = min(starts[s + 1], r1);
        if (a >= b) continue;
        f4_t a0 = (f4_t)(0.f);
        f4_t a1 = (f4_t)(0.f);
        int r = a + rg;
        for (; r + 28 < b; r += 32) {
            const f4_t* p = b4 + (size_t)r * F4 + lane;
            f4_t v0 = __builtin_nontemporal_load(p + 0 * 4 * F4);
            f4_t v1 = __builtin_nontemporal_load(p + 1 * 4 * F4);
            f4_t v2 = __builtin_nontemporal_load(p + 2 * 4 * F4);
            f4_t v3 = __builtin_nontemporal_load(p + 3 * 4 * F4);
            f4_t v4 = __builtin_nontemporal_load(p + 4 * 4 * F4);
            f4_t v5 = __builtin_nontemporal_load(p + 5 * 4 * F4);
            f4_t v6 = __builtin_nontemporal_load(p + 6 * 4 * F4);
            f4_t v7 = __builtin_nontemporal_load(p + 7 * 4 * F4);
            a0 += v0; a1 += v1;
            a0 += v2; a1 += v3;
            a0 += v4; a1 += v5;
            a0 += v6; a1 += v7;
        }
        for (; r < b; r += 4) {
            a0 += __builtin_nontemporal_load(b4 + (size_t)r * F4 + lane);
        }
        a0 += a1;

        red[rg][lane] = a0;
        __syncthreads();
        if (rg == 0) {
            f4_t t = red[0][lane] + red[1][lane] + red[2][lane] + red[3][lane];
            float* dst = sums + (size_t)s * FEAT + lane * 4;
            atomicAdd(dst + 0, t.x);
            atomicAdd(dst + 1, t.y);
            atomicAdd(dst + 2, t.z);
            atomicAdd(dst + 3, t.w);
        }
        __syncthreads();
    }
}

// Broadcast segments overlapping chunk [r0,r1) whose END satisfies the
// half-split condition: (sb <= limit) if LE, else (sb > limit).
template <bool LE>
__device__ __forceinline__ void bcast_chunk_body(
        const int* __restrict__ seg, const int* __restrict__ starts,
        const float* __restrict__ sums, f4_t* __restrict__ o4,
        int r0, int r1, int limit, int lane, int rg, int nrg) {
    const int s0 = seg[r0];
    const int s1 = seg[r1 - 1];
    const f4_t* m4 = (const f4_t*)sums;
    for (int s = s0; s <= s1; ++s) {
        const int sa = starts[s];
        const int sb = starts[s + 1];
        if (LE ? (sb > limit) : (sb <= limit)) continue;
        const int a = max(sa, r0);
        const int b = min(sb, r1);
        if (a >= b) continue;
        const float inv = 1.0f / (float)(sb - sa);
        const f4_t mean = m4[(size_t)s * F4 + lane] * inv;
        int r = a + rg;
        for (; r + 7 * nrg < b; r += 8 * nrg) {
            f4_t* q = o4 + (size_t)r * F4 + lane;
            __builtin_nontemporal_store(mean, q + 0 * nrg * F4);
            __builtin_nontemporal_store(mean, q + 1 * nrg * F4);
            __builtin_nontemporal_store(mean, q + 2 * nrg * F4);
            __builtin_nontemporal_store(mean, q + 3 * nrg * F4);
            __builtin_nontemporal_store(mean, q + 4 * nrg * F4);
            __builtin_nontemporal_store(mean, q + 5 * nrg * F4);
            __builtin_nontemporal_store(mean, q + 6 * nrg * F4);
            __builtin_nontemporal_store(mean, q + 7 * nrg * F4);
        }
        for (; r < b; r += nrg) {
            __builtin_nontemporal_store(mean, o4 + (size_t)r * F4 + lane);
        }
    }
}

// ---------------- K2a: sum half A ----------------
__global__ __launch_bounds__(512) void sum_a_kernel(
        const float* __restrict__ batch, const int* __restrict__ seg,
        const int* __restrict__ starts, float* __restrict__ sums, int total) {
    __shared__ f4_t red[4][F4];
    const int r0 = blockIdx.x * CHUNK;
    if (r0 >= total) return;
    const int r1 = min(r0 + CHUNK, total);
    sum_chunk_body((const f4_t*)batch, seg, starts, sums, red, r0, r1,
                   threadIdx.x & (F4 - 1), threadIdx.x >> 7);
}

// ---------------- K_mid: broadcast half A  ||  sum half B ----------------
// Blocks [0, halfc): broadcast role (segments ending in half A — sums done).
// Blocks [halfc, n): sum role for half-B chunks. Disjoint work, no fences;
// all blocks co-resident -> mixed read+write HBM stream.
__global__ __launch_bounds__(512) void mid_kernel(
        const float* __restrict__ batch, const int* __restrict__ seg,
        const int* __restrict__ starts, float* __restrict__ sums,
        float* __restrict__ out, int total, int halfc, int half_rows) {
    __shared__ f4_t red[4][F4];
    const int lane = threadIdx.x & (F4 - 1);
    const int rg   = threadIdx.x >> 7;         // 0..3
    const int bid  = blockIdx.x;
    if (bid < halfc) {
        const int r0 = bid * CHUNK;
        if (r0 >= total) return;
        const int r1 = min(r0 + CHUNK, total);
        bcast_chunk_body<true>(seg, starts, sums, (f4_t*)out,
                               r0, r1, half_rows, lane, rg, 4);
    } else {
        const int r0 = bid * CHUNK;
        if (r0 >= total) return;
        const int r1 = min(r0 + CHUNK, total);
        sum_chunk_body((const f4_t*)batch, seg, starts, sums, red, r0, r1, lane, rg);
    }
}

// ---------------- K3b: broadcast remaining segments (sb > half_rows) ----------
__global__ __launch_bounds__(512) void bcast_b_kernel(
        const int* __restrict__ seg, const int* __restrict__ starts,
        const float* __restrict__ sums, float* __restrict__ out,
        int total, int half_rows) {
    const int r0 = blockIdx.x * CHUNK;
    if (r0 >= total) return;
    const int r1 = min(r0 + CHUNK, total);
    bcast_chunk_body<false>(seg, starts, sums, (f4_t*)out,
                            r0, r1, half_rows, threadIdx.x & (F4 - 1),
                            threadIdx.x >> 7, 4);
}

// ---------------- Fallback: R5 fused kernel (needs only ~4KB ws) --------------
__global__ __launch_bounds__(512) void seg_mean_fused_kernel(
        const float* __restrict__ batch,
        const int* __restrict__ starts,
        float* __restrict__ out) {
    const int s      = blockIdx.x;
    const int tid    = threadIdx.x;
    const int lane_f = tid & (F4 - 1);
    const int rgrp   = tid >> 7;

    const int start = starts[s];
    const int end   = starts[s + 1];
    const int count = end - start;

    const f4_t* b4 = (const f4_t*)batch;
    f4_t a0 = (f4_t)(0.f);
    f4_t a1 = (f4_t)(0.f);

    int r = start + rgrp;
    for (; r + 28 < end; r += 32) {
        const f4_t* p = b4 + (size_t)r * F4 + lane_f;
        f4_t v0 = __builtin_nontemporal_load(p + 0 * 4 * F4);
        f4_t v1 = __builtin_nontemporal_load(p + 1 * 4 * F4);
        f4_t v2 = __builtin_nontemporal_load(p + 2 * 4 * F4);
        f4_t v3 = __builtin_nontemporal_load(p + 3 * 4 * F4);
        f4_t v4 = __builtin_nontemporal_load(p + 4 * 4 * F4);
        f4_t v5 = __builtin_nontemporal_load(p + 5 * 4 * F4);
        f4_t v6 = __builtin_nontemporal_load(p + 6 * 4 * F4);
        f4_t v7 = __builtin_nontemporal_load(p + 7 * 4 * F4);
        a0 += v0; a1 += v1;
        a0 += v2; a1 += v3;
        a0 += v4; a1 += v5;
        a0 += v6; a1 += v7;
    }
    for (; r < end; r += 4) {
        a0 += __builtin_nontemporal_load(b4 + (size_t)r * F4 + lane_f);
    }
    a0 += a1;

    __shared__ f4_t red[4][F4];
    red[rgrp][lane_f] = a0;
    __syncthreads();

    if (rgrp == 0) {
        f4_t p0 = red[0][lane_f];
        f4_t p1 = red[1][lane_f];
        f4_t p2 = red[2][lane_f];
        f4_t p3 = red[3][lane_f];
        const float inv = 1.0f / (float)(count > 0 ? count : 1);
        red[0][lane_f] = (p0 + p1 + p2 + p3) * inv;
    }
    __syncthreads();

    const f4_t mean = red[0][lane_f];
    f4_t* o4 = (f4_t*)out;

    r = start + rgrp;
    for (; r + 28 < end; r += 32) {
        f4_t* q = o4 + (size_t)r * F4 + lane_f;
        __builtin_nontemporal_store(mean, q + 0 * 4 * F4);
        __builtin_nontemporal_store(mean, q + 1 * 4 * F4);
        __builtin_nontemporal_store(mean, q + 2 * 4 * F4);
        __builtin_nontemporal_store(mean, q + 3 * 4 * F4);
        __builtin_nontemporal_store(mean, q + 4 * 4 * F4);
        __builtin_nontemporal_store(mean, q + 5 * 4 * F4);
        __builtin_nontemporal_store(mean, q + 6 * 4 * F4);
        __builtin_nontemporal_store(mean, q + 7 * 4 * F4);
    }
    for (; r < end; r += 4) {
        __builtin_nontemporal_store(mean, o4 + (size_t)r * F4 + lane_f);
    }
}

extern "C" void kernel_launch(void* const* d_in, const int* in_sizes, int n_in,
                              void* d_out, int out_size, void* d_ws, size_t ws_size,
                              hipStream_t stream) {
    const float* batch = (const float*)d_in[0];
    const int*   seg   = (const int*)d_in[1];
    float*       out   = (float*)d_out;
    const int total    = in_sizes[1];

    // ws layout: [sums: 2MB][starts: (NSEG+1)*4]
    const size_t sums_bytes = (size_t)NSEG * FEAT * sizeof(float);
    const size_t need       = sums_bytes + (NSEG + 1) * sizeof(int);

    const int nblk256 = (total + 255) / 256;

    if (ws_size >= need) {
        float* sums   = (float*)d_ws;
        int*   starts = (int*)((char*)d_ws + sums_bytes);

        const int nchunks   = (total + CHUNK - 1) / CHUNK;
        const int halfc     = nchunks / 2;
        const int half_rows = halfc * CHUNK;

        bounds_zero_kernel<<<nblk256, 256, 0, stream>>>(seg, starts, sums, total);
        sum_a_kernel<<<halfc, 512, 0, stream>>>(batch, seg, starts, sums, half_rows);
        mid_kernel<<<nchunks, 512, 0, stream>>>(batch, seg, starts, sums, out,
                                                total, halfc, half_rows);
        bcast_b_kernel<<<nchunks, 512, 0, stream>>>(seg, starts, sums, out,
                                                    total, half_rows);
    } else {
        int* starts = (int*)d_ws;
        bounds_zero_kernel<<<nblk256, 256, 0, stream>>>(seg, starts, nullptr, total);
        seg_mean_fused_kernel<<<NSEG, 512, 0, stream>>>(batch, starts, out);
    }
}

// Round 14
// 197.749 us; speedup vs baseline: 5.0676x; 1.0279x over previous
//
#include <hip/hip_runtime.h>

#define FEAT 512
#define F4   128          // float4 per row
#define NSEG 1024
#define CHUNK 256         // rows per block in sum/broadcast passes

typedef float f4_t __attribute__((ext_vector_type(4)));

// ---------------- K1: segment boundaries + zero sums ----------------
// starts[s] = first row index with seg_id >= s (seg ids sorted).
// Zeroing done here in-kernel (rocclr fill node for 2MB is pathological, R2).
__global__ void bounds_zero_kernel(const int* __restrict__ seg,
                                   int* __restrict__ starts,
                                   float* __restrict__ sums, int total) {
    int i = blockIdx.x * blockDim.x + threadIdx.x;
    if (sums != nullptr && i < NSEG * FEAT / 2) {
        ((float2*)sums)[i] = make_float2(0.f, 0.f);
    }
    if (i >= total) return;
    int cur = seg[i];
    int prev = (i == 0) ? -1 : seg[i - 1];
    for (int s = prev + 1; s <= cur; ++s) starts[s] = i;
    if (i == total - 1) {
        for (int s = cur + 1; s <= NSEG; ++s) starts[s] = total;
    }
}

// ---------------- K2: chunk-balanced partial sums (read 512MB, NT) ------------
// Measured read-accumulate rate ~4.6 TB/s — invariant under balance (R7),
// deeper SW pipeline (R9), cached loads (R12, −11µs), concurrent mixing (R13).
// NT loads: +11µs if removed. x8 unroll: +34µs if removed.
__global__ __launch_bounds__(512) void chunk_sum_kernel(
        const float* __restrict__ batch,
        const int* __restrict__ seg,
        const int* __restrict__ starts,
        float* __restrict__ sums, int total) {
    const int tid  = threadIdx.x;
    const int lane = tid & (F4 - 1);   // f4 column 0..127
    const int rg   = tid >> 7;         // row-group 0..3
    const int r0   = blockIdx.x * CHUNK;
    if (r0 >= total) return;
    const int r1   = min(r0 + CHUNK, total);

    const int s0 = seg[r0];
    const int s1 = seg[r1 - 1];

    const f4_t* b4 = (const f4_t*)batch;
    __shared__ f4_t red[4][F4];

    for (int s = s0; s <= s1; ++s) {
        const int a = max(starts[s], r0);      // block-uniform
        const int b = min(starts[s + 1], r1);  // block-uniform
        if (a >= b) continue;                  // uniform skip (empty segment)

        f4_t a0 = (f4_t)(0.f);
        f4_t a1 = (f4_t)(0.f);
        int r = a + rg;
        for (; r + 28 < b; r += 32) {
            const f4_t* p = b4 + (size_t)r * F4 + lane;
            f4_t v0 = __builtin_nontemporal_load(p + 0 * 4 * F4);
            f4_t v1 = __builtin_nontemporal_load(p + 1 * 4 * F4);
            f4_t v2 = __builtin_nontemporal_load(p + 2 * 4 * F4);
            f4_t v3 = __builtin_nontemporal_load(p + 3 * 4 * F4);
            f4_t v4 = __builtin_nontemporal_load(p + 4 * 4 * F4);
            f4_t v5 = __builtin_nontemporal_load(p + 5 * 4 * F4);
            f4_t v6 = __builtin_nontemporal_load(p + 6 * 4 * F4);
            f4_t v7 = __builtin_nontemporal_load(p + 7 * 4 * F4);
            a0 += v0; a1 += v1;
            a0 += v2; a1 += v3;
            a0 += v4; a1 += v5;
            a0 += v6; a1 += v7;
        }
        for (; r < b; r += 4) {
            a0 += __builtin_nontemporal_load(b4 + (size_t)r * F4 + lane);
        }
        a0 += a1;

        red[rg][lane] = a0;
        __syncthreads();
        if (rg == 0) {
            f4_t t = red[0][lane] + red[1][lane] + red[2][lane] + red[3][lane];
            float* dst = sums + (size_t)s * FEAT + lane * 4;
            atomicAdd(dst + 0, t.x);
            atomicAdd(dst + 1, t.y);
            atomicAdd(dst + 2, t.z);
            atomicAdd(dst + 3, t.w);
        }
        __syncthreads();
    }
}

// ---------------- K3: chunk-balanced broadcast (write 512MB, NT) --------------
// Fill-class: ~6.6 TB/s. NT stores: +30µs if removed. Balance: +12µs if removed.
__global__ __launch_bounds__(256) void broadcast_chunk_kernel(
        const int* __restrict__ seg,
        const int* __restrict__ starts,
        const float* __restrict__ sums,
        float* __restrict__ out, int total) {
    const int tid  = threadIdx.x;
    const int lane = tid & (F4 - 1);   // f4 column 0..127
    const int rg   = tid >> 7;         // row-group 0..1
    const int r0   = blockIdx.x * CHUNK;
    if (r0 >= total) return;
    const int r1   = min(r0 + CHUNK, total);

    const int s0 = seg[r0];
    const int s1 = seg[r1 - 1];

    const f4_t* m4 = (const f4_t*)sums;
    f4_t* o4 = (f4_t*)out;

    for (int s = s0; s <= s1; ++s) {
        const int sa = starts[s];
        const int sb = starts[s + 1];
        const int a = max(sa, r0);
        const int b = min(sb, r1);
        if (a >= b) continue;
        const int count = sb - sa;
        const float inv = 1.0f / (float)(count > 0 ? count : 1);
        const f4_t mean = m4[(size_t)s * F4 + lane] * inv;
        int r = a + rg;
        for (; r + 14 < b; r += 16) {
            f4_t* q = o4 + (size_t)r * F4 + lane;
            __builtin_nontemporal_store(mean, q + 0 * 2 * F4);
            __builtin_nontemporal_store(mean, q + 1 * 2 * F4);
            __builtin_nontemporal_store(mean, q + 2 * 2 * F4);
            __builtin_nontemporal_store(mean, q + 3 * 2 * F4);
            __builtin_nontemporal_store(mean, q + 4 * 2 * F4);
            __builtin_nontemporal_store(mean, q + 5 * 2 * F4);
            __builtin_nontemporal_store(mean, q + 6 * 2 * F4);
            __builtin_nontemporal_store(mean, q + 7 * 2 * F4);
        }
        for (; r < b; r += 2) {
            __builtin_nontemporal_store(mean, o4 + (size_t)r * F4 + lane);
        }
    }
}

// ---------------- Fallback: fused kernel (needs only ~4KB ws) --------------
__global__ __launch_bounds__(512) void seg_mean_fused_kernel(
        const float* __restrict__ batch,
        const int* __restrict__ starts,
        float* __restrict__ out) {
    const int s      = blockIdx.x;
    const int tid    = threadIdx.x;
    const int lane_f = tid & (F4 - 1);
    const int rgrp   = tid >> 7;

    const int start = starts[s];
    const int end   = starts[s + 1];
    const int count = end - start;

    const f4_t* b4 = (const f4_t*)batch;
    f4_t a0 = (f4_t)(0.f);
    f4_t a1 = (f4_t)(0.f);

    int r = start + rgrp;
    for (; r + 28 < end; r += 32) {
        const f4_t* p = b4 + (size_t)r * F4 + lane_f;
        f4_t v0 = __builtin_nontemporal_load(p + 0 * 4 * F4);
        f4_t v1 = __builtin_nontemporal_load(p + 1 * 4 * F4);
        f4_t v2 = __builtin_nontemporal_load(p + 2 * 4 * F4);
        f4_t v3 = __builtin_nontemporal_load(p + 3 * 4 * F4);
        f4_t v4 = __builtin_nontemporal_load(p + 4 * 4 * F4);
        f4_t v5 = __builtin_nontemporal_load(p + 5 * 4 * F4);
        f4_t v6 = __builtin_nontemporal_load(p + 6 * 4 * F4);
        f4_t v7 = __builtin_nontemporal_load(p + 7 * 4 * F4);
        a0 += v0; a1 += v1;
        a0 += v2; a1 += v3;
        a0 += v4; a1 += v5;
        a0 += v6; a1 += v7;
    }
    for (; r < end; r += 4) {
        a0 += __builtin_nontemporal_load(b4 + (size_t)r * F4 + lane_f);
    }
    a0 += a1;

    __shared__ f4_t red[4][F4];
    red[rgrp][lane_f] = a0;
    __syncthreads();

    if (rgrp == 0) {
        f4_t p0 = red[0][lane_f];
        f4_t p1 = red[1][lane_f];
        f4_t p2 = red[2][lane_f];
        f4_t p3 = red[3][lane_f];
        const float inv = 1.0f / (float)(count > 0 ? count : 1);
        red[0][lane_f] = (p0 + p1 + p2 + p3) * inv;
    }
    __syncthreads();

    const f4_t mean = red[0][lane_f];
    f4_t* o4 = (f4_t*)out;

    r = start + rgrp;
    for (; r + 28 < end; r += 32) {
        f4_t* q = o4 + (size_t)r * F4 + lane_f;
        __builtin_nontemporal_store(mean, q + 0 * 4 * F4);
        __builtin_nontemporal_store(mean, q + 1 * 4 * F4);
        __builtin_nontemporal_store(mean, q + 2 * 4 * F4);
        __builtin_nontemporal_store(mean, q + 3 * 4 * F4);
        __builtin_nontemporal_store(mean, q + 4 * 4 * F4);
        __builtin_nontemporal_store(mean, q + 5 * 4 * F4);
        __builtin_nontemporal_store(mean, q + 6 * 4 * F4);
        __builtin_nontemporal_store(mean, q + 7 * 4 * F4);
    }
    for (; r < end; r += 4) {
        __builtin_nontemporal_store(mean, o4 + (size_t)r * F4 + lane_f);
    }
}

extern "C" void kernel_launch(void* const* d_in, const int* in_sizes, int n_in,
                              void* d_out, int out_size, void* d_ws, size_t ws_size,
                              hipStream_t stream) {
    const float* batch = (const float*)d_in[0];
    const int*   seg   = (const int*)d_in[1];
    float*       out   = (float*)d_out;
    const int total    = in_sizes[1];

    // ws layout: [sums: 2MB][starts: (NSEG+1)*4]
    const size_t sums_bytes = (size_t)NSEG * FEAT * sizeof(float);
    const size_t need       = sums_bytes + (NSEG + 1) * sizeof(int);

    const int nblk256 = (total + 255) / 256;

    if (ws_size >= need) {
        float* sums   = (float*)d_ws;
        int*   starts = (int*)((char*)d_ws + sums_bytes);

        bounds_zero_kernel<<<nblk256, 256, 0, stream>>>(seg, starts, sums, total);
        const int nchunks = (total + CHUNK - 1) / CHUNK;
        chunk_sum_kernel<<<nchunks, 512, 0, stream>>>(batch, seg, starts, sums, total);
        broadcast_chunk_kernel<<<nchunks, 256, 0, stream>>>(seg, starts, sums, out, total);
    } else {
        int* starts = (int*)d_ws;
        bounds_zero_kernel<<<nblk256, 256, 0, stream>>>(seg, starts, nullptr, total);
        seg_mean_fused_kernel<<<NSEG, 512, 0, stream>>>(batch, starts, out);
    }
}